// Round 1
// 2316.507 us; speedup vs baseline: 4.8092x; 4.8092x over previous
//
#include <hip/hip_runtime.h>
#include <stdint.h>

#define B_  64
#define T_  1000
#define DI_ 128
#define DR_ 512
#define DO_ 64

// ---------- bf16 helpers ----------
static __device__ __forceinline__ float bfu(uint16_t u){
  union{uint32_t i; float f;} v; v.i = ((uint32_t)u) << 16; return v.f;
}
static __device__ __forceinline__ uint16_t f2bf(float f){
  union{float f; uint32_t i;} v; v.f = f;
  uint32_t i = v.i;
  return (uint16_t)((i + 0x7FFFu + ((i >> 16) & 1u)) >> 16);   // RNE
}

// ---------- dtype-generic scalar IO ----------
template<int BF16> struct IO;
template<> struct IO<1> {
  static __device__ __forceinline__ float ld(const void* p, size_t i){ return bfu(((const uint16_t*)p)[i]); }
  static __device__ __forceinline__ void  st(void* p, size_t i, float v){ ((uint16_t*)p)[i] = f2bf(v); }
};
template<> struct IO<0> {
  static __device__ __forceinline__ float ld(const void* p, size_t i){ return ((const float*)p)[i]; }
  static __device__ __forceinline__ void  st(void* p, size_t i, float v){ ((float*)p)[i] = v; }
};

static __device__ __forceinline__ float retanh_f(float x){
  if (x <= 0.f) return 0.f;
  float e = __expf(2.f * x);
  return 1.f - 2.f / (e + 1.f);
}

// ---------- init: dtype detect + zero tagged exchange buffer ----------
// rglob tags persist in d_ws across bench reps; a stale tag==t+1 from the
// previous run would satisfy a poll with old data, so zero all 2*B*DR slots.
__global__ void init_kernel(const uint16_t* __restrict__ bx, int* __restrict__ flag,
                            unsigned long long* __restrict__ rglob){
  size_t i = (size_t)blockIdx.x * blockDim.x + threadIdx.x;
  if (i < (size_t)2 * B_ * DR_) rglob[i] = 0ull;
  if (i == 0) {
    int small = 0;
    for (int k = 0; k < 24; ++k) {
      uint16_t u = bx[2 * k];
      uint16_t e = (u >> 7) & 0xFF;
      small += (e <= 124) ? 1 : 0;
    }
    *flag = (small == 24) ? 1 : 0;
  }
}

// ---------- recurrent scan ----------
// 256 blocks = 64 batches x 4 unit-slices of 128 rows. blk = s*64 + b so all 4
// slices of batch b share blk%8 (same-XCD heuristic; correctness does NOT
// depend on it). Thread (q, rl): q = tid>>7 (col quarter), rl = tid&127.
// Wrr slice rows held in VGPRs/AGPRs (128 f32/thread). r state via LDS.
//
// Cross-slice exchange (NEW): fence-free. Each published value is a single
// 8-byte RELAXED agent-scope atomic {f32 value, u32 tag = t+1} into a
// double-buffered rglob[2][B][DR]. Readers (waves 2..7) spin on their own
// packet until the tag matches; single-copy atomicity of the 8B store makes
// acquire/release fences (buffer_wbl2 / buffer_inv -> the old 10us/step)
// unnecessary. Overwrite safety: a block can only reach the publish of step
// t+2 (same buffer parity as t) after it observed everyone's tag t+2, which
// each block only publishes after it consumed step-t data.
template<int BF16>
__global__ __launch_bounds__(512)
void rnn_run(const void* __restrict__ inp,   // [B,T,DI]
             const void* __restrict__ br,    // [B,T,DR]
             const void* __restrict__ Wrx,   // [DR,DI]
             const void* __restrict__ bx,    // [DR]
             const void* __restrict__ Wrr,   // [DR,DR]
             const void* __restrict__ r0,    // [DR]
             void* __restrict__ rstore,      // [B,T,DR]
             const int* __restrict__ flag,
             unsigned long long* __restrict__ rglob)  // [2][B][DR] tagged
{
  if (*flag != BF16) return;
  const int blk = blockIdx.x;
  const int b   = blk & 63;
  const int s   = blk >> 6;          // slice 0..3
  const int tid = threadIdx.x;
  const int q   = tid >> 7;          // col quarter 0..3 (wave-uniform)
  const int rl  = tid & 127;         // local row 0..127
  const int row = s * 128 + rl;      // global unit index this thread serves

  __shared__ __align__(16) float s_r[DR_];
  __shared__ __align__(16) float s_in[DI_];
  __shared__ __align__(16) float s_part[DR_];   // [rl*4 + q]

  // ---- weights in registers ----
  float w[128];
  #pragma unroll
  for (int k = 0; k < 128; ++k)
    w[k] = IO<BF16>::ld(Wrr, (size_t)row * DR_ + q * 128 + k);
  float wx[32];
  #pragma unroll
  for (int k = 0; k < 32; ++k)
    wx[k] = IO<BF16>::ld(Wrx, (size_t)row * DI_ + q * 32 + k);

  const float bxj = (q == 0) ? IO<BF16>::ld(bx, row) : 0.f;
  float rj        = (q == 0) ? IO<BF16>::ld(r0, row) : 0.f;

  s_r[tid & 511] = IO<BF16>::ld(r0, tid & 511);     // full r(-1) = r0
  if (tid < DI_) s_in[tid] = IO<BF16>::ld(inp, (size_t)b * T_ * DI_ + tid);

  // reader mapping: threads 128..511 (waves 2..7) pull the 384 remote rows
  const int j = tid - 128;
  const int g = j + ((j >= s * 128) ? 128 : 0);

  const size_t base_in = (size_t)b * T_ * DI_;
  const size_t base_r  = (size_t)b * T_ * DR_;
  const size_t ex_base = (size_t)b * DR_;
  bool ok = true;                   // poll timeout guard (never trips co-resident)
  __syncthreads();

  #pragma unroll 1
  for (int t = 0; t < T_; ++t) {
    // early-issue global loads for this step's update / next step's input (q0)
    float brv = 0.f, inv = 0.f;
    if (q == 0) {
      brv = IO<BF16>::ld(br, base_r + (size_t)t * DR_ + row);
      if (t + 1 < T_)
        inv = IO<BF16>::ld(inp, base_in + (size_t)(t + 1) * DI_ + rl);
    }

    // ---- partial dot: cols q*128.. of Wrr row, q*32.. of Wrx row ----
    float a0 = 0.f, a1 = 0.f, a2 = 0.f, a3 = 0.f;
    const float* rq = s_r + q * 128;
    #pragma unroll
    for (int k = 0; k < 128; k += 4) {
      float4 rv = *(const float4*)(rq + k);          // wave-uniform -> broadcast
      a0 = fmaf(w[k + 0], rv.x, a0);
      a1 = fmaf(w[k + 1], rv.y, a1);
      a2 = fmaf(w[k + 2], rv.z, a2);
      a3 = fmaf(w[k + 3], rv.w, a3);
    }
    const float* iq = s_in + q * 32;
    #pragma unroll
    for (int k = 0; k < 32; k += 4) {
      float4 iv = *(const float4*)(iq + k);
      a0 = fmaf(wx[k + 0], iv.x, a0);
      a1 = fmaf(wx[k + 1], iv.y, a1);
      a2 = fmaf(wx[k + 2], iv.z, a2);
      a3 = fmaf(wx[k + 3], iv.w, a3);
    }
    s_part[rl * 4 + q] = (a0 + a1) + (a2 + a3);
    __syncthreads();                                  // B1: partials ready

    const size_t slot = ((size_t)(t & 1) * B_) * DR_;

    if (q == 0) {
      // ---- pointwise update + tagged publish ----
      float4 p  = *(const float4*)(s_part + rl * 4);
      float tot = (p.x + p.y) + (p.z + p.w) + bxj;
      float f   = retanh_f(tot);
      rj = rj + 0.1f * (f + brv - rj);                // a = DT/TAU
      IO<BF16>::st(rstore, base_r + (size_t)t * DR_ + row, rj);
      s_r[row] = rj;
      if (t + 1 < T_) {
        s_in[rl] = inv;                               // stage next input
        union { float f; unsigned u; } cv; cv.f = rj;
        unsigned long long pkt =
            ((unsigned long long)(unsigned)(t + 1) << 32) | (unsigned long long)cv.u;
        __hip_atomic_store(&rglob[slot + ex_base + row], pkt,
                           __ATOMIC_RELAXED, __HIP_MEMORY_SCOPE_AGENT);
      }
    } else if (t + 1 < T_) {
      // ---- poll own remote packet until its tag == t+1 ----
      const unsigned want = (unsigned)(t + 1);
      unsigned long long v;
      if (ok) {
        int spins = 50000;
        for (;;) {
          v = __hip_atomic_load(&rglob[slot + ex_base + g],
                                __ATOMIC_RELAXED, __HIP_MEMORY_SCOPE_AGENT);
          if ((unsigned)(v >> 32) == want) break;
          __builtin_amdgcn_s_sleep(1);
          if (--spins == 0) { ok = false; break; }    // never trips when co-resident
        }
      } else {
        v = __hip_atomic_load(&rglob[slot + ex_base + g],
                              __ATOMIC_RELAXED, __HIP_MEMORY_SCOPE_AGENT);
      }
      union { unsigned u; float f; } cv; cv.u = (unsigned)v;
      s_r[g] = cv.f;
    }
    __syncthreads();                                  // B2: s_r(t), s_in(t+1) complete
  }
}

// ---------- output projection: y = rstore @ Wyr^T + by ----------
template<int BF16>
__global__ __launch_bounds__(256)
void ygemm(const void* __restrict__ Wyr,     // [DO,DR]
           const void* __restrict__ by,      // [DO]
           const void* __restrict__ rstore,  // [B*T, DR]
           void* __restrict__ y,             // [B*T, DO]
           const int* __restrict__ flag)
{
  if (*flag != BF16) return;
  const int tid  = threadIdx.x;
  const int wave = tid >> 6;
  const int lane = tid & 63;
  const int base = blockIdx.x * 64;          // first row of this block

  __shared__ __align__(16) float rs_c[64 * 128];        // 32 KB
  __shared__ __align__(16) float wy_c[64 * 132];        // 33.8 KB (pad vs bank hits)

  float acc[16];
  #pragma unroll
  for (int i = 0; i < 16; ++i) acc[i] = 0.f;

  #pragma unroll 1
  for (int kc = 0; kc < 4; ++kc) {
    for (int n = tid; n < 8192; n += 256) {
      int r = n >> 7, k = n & 127;
      rs_c[r * 128 + k] = IO<BF16>::ld(rstore, (size_t)(base + r) * DR_ + kc * 128 + k);
    }
    for (int n = tid; n < 8192; n += 256) {
      int o = n >> 7, k = n & 127;
      wy_c[o * 132 + k] = IO<BF16>::ld(Wyr, (size_t)o * DR_ + kc * 128 + k);
    }
    __syncthreads();

    float4 wf[32];
    #pragma unroll
    for (int m = 0; m < 32; ++m)
      wf[m] = *(const float4*)(wy_c + lane * 132 + m * 4);

    #pragma unroll 1
    for (int i = 0; i < 16; ++i) {
      int r = wave * 16 + i;
      float s0 = 0.f, s1 = 0.f, s2 = 0.f, s3 = 0.f;
      #pragma unroll
      for (int m = 0; m < 32; ++m) {
        float4 rv = *(const float4*)(rs_c + r * 128 + m * 4);   // broadcast
        s0 = fmaf(wf[m].x, rv.x, s0);
        s1 = fmaf(wf[m].y, rv.y, s1);
        s2 = fmaf(wf[m].z, rv.z, s2);
        s3 = fmaf(wf[m].w, rv.w, s3);
      }
      acc[i] += (s0 + s1) + (s2 + s3);
    }
    __syncthreads();
  }

  const float byl = IO<BF16>::ld(by, lane);
  #pragma unroll
  for (int i = 0; i < 16; ++i) {
    int r = base + wave * 16 + i;
    IO<BF16>::st(y, (size_t)r * DO_ + lane, acc[i] + byl);
  }
}

extern "C" void kernel_launch(void* const* d_in, const int* in_sizes, int n_in,
                              void* d_out, int out_size, void* d_ws, size_t ws_size,
                              hipStream_t stream) {
  const void* inp = d_in[0];
  const void* brn = d_in[1];
  const void* Wrx = d_in[2];
  const void* bx  = d_in[3];
  const void* Wrr = d_in[4];
  const void* Wyr = d_in[5];
  const void* by  = d_in[6];
  const void* r0  = d_in[7];

  // workspace layout: [0] dtype flag | [256] rglob[2][B][DR] tagged u64 (512 KB)
  char* ws = (char*)d_ws;
  int*                flag  = (int*)ws;
  unsigned long long* rglob = (unsigned long long*)(ws + 256);

  uint16_t* y_bf  = (uint16_t*)d_out;
  uint16_t* rs_bf = y_bf + (size_t)B_ * T_ * DO_;
  float*    y_f   = (float*)d_out;
  float*    rs_f  = y_f + (size_t)B_ * T_ * DO_;

  hipLaunchKernelGGL(init_kernel, dim3(256), dim3(256), 0, stream,
                     (const uint16_t*)bx, flag, rglob);

  hipLaunchKernelGGL((rnn_run<1>), dim3(4 * B_), dim3(512), 0, stream,
                     inp, brn, Wrx, bx, Wrr, r0, (void*)rs_bf, flag, rglob);
  hipLaunchKernelGGL((rnn_run<0>), dim3(4 * B_), dim3(512), 0, stream,
                     inp, brn, Wrx, bx, Wrr, r0, (void*)rs_f, flag, rglob);

  hipLaunchKernelGGL((ygemm<1>), dim3((B_ * T_) / 64), dim3(256), 0, stream,
                     Wyr, by, (const void*)rs_bf, (void*)y_bf, flag);
  hipLaunchKernelGGL((ygemm<0>), dim3((B_ * T_) / 64), dim3(256), 0, stream,
                     Wyr, by, (const void*)rs_f, (void*)y_f, flag);
}